// Round 1
// baseline (138.067 us; speedup 1.0000x reference)
//
#include <hip/hip_runtime.h>

#define GS 64
#define BB 128
#define NN 8192
#define KK 3

__device__ __forceinline__ float dist2(float x, float y, float z,
                                       const float* __restrict__ cpb) {
    float fx = fminf(fmaxf(floorf((x + 0.5f) * 64.0f), 0.0f), 63.0f);
    float fy = fminf(fmaxf(floorf((y + 0.5f) * 64.0f), 0.0f), 63.0f);
    float fz = fminf(fmaxf(floorf((z + 0.5f) * 64.0f), 0.0f), 63.0f);
    int ix = (int)fx, iy = (int)fy, iz = (int)fz;
    int flat = (ix * GS + iy) * GS + iz;
    const float* c = cpb + (size_t)flat * 3;
    float dx = x - c[0];
    float dy = y - c[1];
    float dz = z - c[2];
    return dx * dx + dy * dy + dz * dz;
}

__global__ void init_ws_kernel(double* ws) {
    if (threadIdx.x < 2) ws[threadIdx.x] = 0.0;
}

__global__ __launch_bounds__(256) void symloss_main(
    const float* __restrict__ points, const float* __restrict__ cp,
    const float* __restrict__ plane, const float* __restrict__ quat,
    double* __restrict__ ws) {
    int id = blockIdx.x * 256 + threadIdx.x;
    int b = id >> 13;          // N = 8192 points per b
    int n = id & (NN - 1);

    const float* p = points + ((size_t)b * NN + n) * 3;
    float px = p[0], py = p[1], pz = p[2];
    const float* cpb = cp + (size_t)b * (GS * GS * GS) * 3;

    float ref_acc = 0.0f, rot_acc = 0.0f;

#pragma unroll
    for (int k = 0; k < KK; ++k) {
        // ---- reflect ----
        const float* pl = plane + ((size_t)k * BB + b) * 4;
        float nx = pl[0], ny = pl[1], nz = pl[2], d = pl[3];
        float denom = nx * nx + ny * ny + nz * nz + 1e-12f;
        float t = (px * nx + py * ny + pz * nz + d) / denom;
        float rx = px - 2.0f * t * nx;
        float ry = py - 2.0f * t * ny;
        float rz = pz - 2.0f * t * nz;
        ref_acc += dist2(rx, ry, rz, cpb);

        // ---- rotate ----
        const float* q = quat + ((size_t)k * BB + b) * 4;
        float qw = q[0], qx = q[1], qy = q[2], qz = q[3];
        float qn = sqrtf(qw * qw + qx * qx + qy * qy + qz * qz) + 1e-12f;
        qw /= qn; qx /= qn; qy /= qn; qz /= qn;
        // uv = cross(v, p)
        float ux = qy * pz - qz * py;
        float uy = qz * px - qx * pz;
        float uz = qx * py - qy * px;
        // s = uv + w*p
        float sx = ux + qw * px;
        float sy = uy + qw * py;
        float sz = uz + qw * pz;
        // out = p + 2*cross(v, s)
        float ox = px + 2.0f * (qy * sz - qz * sy);
        float oy = py + 2.0f * (qz * sx - qx * sz);
        float oz = pz + 2.0f * (qx * sy - qy * sx);
        rot_acc += dist2(ox, oy, oz, cpb);
    }

    // ---- block reduction: wave shuffle (width 64) -> LDS -> atomic ----
    for (int off = 32; off > 0; off >>= 1) {
        ref_acc += __shfl_down(ref_acc, off, 64);
        rot_acc += __shfl_down(rot_acc, off, 64);
    }
    __shared__ float s_ref[4], s_rot[4];
    int wave = threadIdx.x >> 6;
    int lane = threadIdx.x & 63;
    if (lane == 0) {
        s_ref[wave] = ref_acc;
        s_rot[wave] = rot_acc;
    }
    __syncthreads();
    if (threadIdx.x == 0) {
        float r = s_ref[0] + s_ref[1] + s_ref[2] + s_ref[3];
        float o = s_rot[0] + s_rot[1] + s_rot[2] + s_rot[3];
        atomicAdd(&ws[0], (double)r);
        atomicAdd(&ws[1], (double)o);
    }
}

__global__ void finalize_kernel(const double* __restrict__ ws,
                                float* __restrict__ out) {
    if (threadIdx.x == 0) {
        const double inv = 1.0 / ((double)BB * (double)NN);
        out[0] = (float)(ws[0] * inv);
        out[1] = (float)(ws[1] * inv);
    }
}

extern "C" void kernel_launch(void* const* d_in, const int* in_sizes, int n_in,
                              void* d_out, int out_size, void* d_ws, size_t ws_size,
                              hipStream_t stream) {
    const float* points = (const float*)d_in[0];
    const float* cp     = (const float*)d_in[1];
    // d_in[2] = voxel (unused)
    const float* plane  = (const float*)d_in[3];
    const float* quat   = (const float*)d_in[4];
    float* out = (float*)d_out;
    double* ws = (double*)d_ws;

    init_ws_kernel<<<1, 64, 0, stream>>>(ws);
    int total_points = BB * NN;           // 1,048,576
    int blocks = total_points / 256;      // 4096
    symloss_main<<<blocks, 256, 0, stream>>>(points, cp, plane, quat, ws);
    finalize_kernel<<<1, 64, 0, stream>>>(ws, out);
}

// Round 2
// 124.566 us; speedup vs baseline: 1.1084x; 1.1084x over previous
//
#include <hip/hip_runtime.h>

#define GS 64
#define BB 128
#define NN 8192
#define KK 3

__device__ __forceinline__ float dist2(float x, float y, float z,
                                       const float* __restrict__ cpb) {
    float fx = fminf(fmaxf(floorf((x + 0.5f) * 64.0f), 0.0f), 63.0f);
    float fy = fminf(fmaxf(floorf((y + 0.5f) * 64.0f), 0.0f), 63.0f);
    float fz = fminf(fmaxf(floorf((z + 0.5f) * 64.0f), 0.0f), 63.0f);
    int ix = (int)fx, iy = (int)fy, iz = (int)fz;
    int flat = (ix * GS + iy) * GS + iz;
    const float* c = cpb + (size_t)flat * 3;
    float dx = x - c[0];
    float dy = y - c[1];
    float dz = z - c[2];
    return dx * dx + dy * dy + dz * dz;
}

__global__ void init_ws_kernel(double* ws) {
    if (threadIdx.x < 2) ws[threadIdx.x] = 0.0;
}

__global__ __launch_bounds__(256) void symloss_main(
    const float* __restrict__ points, const float* __restrict__ cp,
    const float* __restrict__ plane, const float* __restrict__ quat,
    double* __restrict__ ws) {
    // XCD-aware bijective swizzle: 4096 blocks, 8 XCDs, hardware assigns
    // XCD = blockIdx % 8 (round-robin). Remap so each XCD gets 512
    // consecutive work items => 16 consecutive b's per XCD => each b's 3MB
    // cp slice stays in ONE XCD's L2.
    int raw  = blockIdx.x;
    int xcd  = raw & 7;
    int slot = raw >> 3;              // 0..511
    int work = xcd * 512 + slot;      // bijective since grid % 8 == 0

    int id = work * 256 + threadIdx.x;
    int b = id >> 13;                 // 8192 points per b
    int n = id & (NN - 1);

    const float* p = points + ((size_t)b * NN + n) * 3;
    float px = p[0], py = p[1], pz = p[2];
    const float* cpb = cp + (size_t)b * (GS * GS * GS) * 3;

    float ref_acc = 0.0f, rot_acc = 0.0f;

#pragma unroll
    for (int k = 0; k < KK; ++k) {
        // ---- reflect ----
        const float* pl = plane + ((size_t)k * BB + b) * 4;
        float nx = pl[0], ny = pl[1], nz = pl[2], d = pl[3];
        float denom = nx * nx + ny * ny + nz * nz + 1e-12f;
        float t = (px * nx + py * ny + pz * nz + d) / denom;
        float rx = px - 2.0f * t * nx;
        float ry = py - 2.0f * t * ny;
        float rz = pz - 2.0f * t * nz;
        ref_acc += dist2(rx, ry, rz, cpb);

        // ---- rotate ----
        const float* q = quat + ((size_t)k * BB + b) * 4;
        float qw = q[0], qx = q[1], qy = q[2], qz = q[3];
        float qn = sqrtf(qw * qw + qx * qx + qy * qy + qz * qz) + 1e-12f;
        qw /= qn; qx /= qn; qy /= qn; qz /= qn;
        float ux = qy * pz - qz * py;
        float uy = qz * px - qx * pz;
        float uz = qx * py - qy * px;
        float sx = ux + qw * px;
        float sy = uy + qw * py;
        float sz = uz + qw * pz;
        float ox = px + 2.0f * (qy * sz - qz * sy);
        float oy = py + 2.0f * (qz * sx - qx * sz);
        float oz = pz + 2.0f * (qx * sy - qy * sx);
        rot_acc += dist2(ox, oy, oz, cpb);
    }

    // ---- block reduction: wave shuffle (width 64) -> LDS -> atomic ----
    for (int off = 32; off > 0; off >>= 1) {
        ref_acc += __shfl_down(ref_acc, off, 64);
        rot_acc += __shfl_down(rot_acc, off, 64);
    }
    __shared__ float s_ref[4], s_rot[4];
    int wave = threadIdx.x >> 6;
    int lane = threadIdx.x & 63;
    if (lane == 0) {
        s_ref[wave] = ref_acc;
        s_rot[wave] = rot_acc;
    }
    __syncthreads();
    if (threadIdx.x == 0) {
        float r = s_ref[0] + s_ref[1] + s_ref[2] + s_ref[3];
        float o = s_rot[0] + s_rot[1] + s_rot[2] + s_rot[3];
        atomicAdd(&ws[0], (double)r);
        atomicAdd(&ws[1], (double)o);
    }
}

__global__ void finalize_kernel(const double* __restrict__ ws,
                                float* __restrict__ out) {
    if (threadIdx.x == 0) {
        const double inv = 1.0 / ((double)BB * (double)NN);
        out[0] = (float)(ws[0] * inv);
        out[1] = (float)(ws[1] * inv);
    }
}

extern "C" void kernel_launch(void* const* d_in, const int* in_sizes, int n_in,
                              void* d_out, int out_size, void* d_ws, size_t ws_size,
                              hipStream_t stream) {
    const float* points = (const float*)d_in[0];
    const float* cp     = (const float*)d_in[1];
    // d_in[2] = voxel (unused)
    const float* plane  = (const float*)d_in[3];
    const float* quat   = (const float*)d_in[4];
    float* out = (float*)d_out;
    double* ws = (double*)d_ws;

    init_ws_kernel<<<1, 64, 0, stream>>>(ws);
    int total_points = BB * NN;           // 1,048,576
    int blocks = total_points / 256;      // 4096
    symloss_main<<<blocks, 256, 0, stream>>>(points, cp, plane, quat, ws);
    finalize_kernel<<<1, 64, 0, stream>>>(ws, out);
}